// Round 8
// baseline (1265.924 us; speedup 1.0000x reference)
//
#include <hip/hip_runtime.h>
#include <hip/hip_bf16.h>

#define T_TOK  2048
#define DIMSZ  2048
#define NEXP   32
#define INTERS 1024
#define SINTER 2048
#define NTOPK  6

typedef __bf16 bf16x8 __attribute__((ext_vector_type(8)));
typedef float  f32x4  __attribute__((ext_vector_type(4)));
typedef unsigned short u16x8 __attribute__((ext_vector_type(8)));

__device__ __forceinline__ unsigned short f2b(float f) {
    __hip_bfloat16 h = __float2bfloat16(f);
    return __builtin_bit_cast(unsigned short, h);
}

// async global->LDS, 16B per lane. LDS dest is wave-uniform base + lane*16.
__device__ __forceinline__ void gl_lds16(const unsigned short* g, unsigned short* l) {
    __builtin_amdgcn_global_load_lds(
        (const __attribute__((address_space(1))) void*)g,
        (__attribute__((address_space(3))) void*)l, 16, 0, 0);
}

// ---- pipelined B staging: 8 float4 regs/thread (128 rows x 64 f32) ----
// thread (srow = tid>>3, sct = tid&7); 4 row-passes of 32.
__device__ __forceinline__ void load_b8(
    const float* __restrict__ B, int n0, int K, int k0,
    int srow, int sct, float4* r)
{
    #pragma unroll
    for (int p = 0; p < 4; ++p) {
        const float* g = B + (size_t)(n0 + p * 32 + srow) * K + k0 + sct * 8;
        r[2 * p]     = *(const float4*)g;
        r[2 * p + 1] = *(const float4*)(g + 4);
    }
}
// convert + write at XOR-swizzled slot (wslot = sct ^ (srow&7); row&7==srow&7)
__device__ __forceinline__ void write_b8(
    unsigned short* __restrict__ Bs, int srow, int wslot, const float4* r)
{
    #pragma unroll
    for (int p = 0; p < 4; ++p) {
        float4 a = r[2 * p], b = r[2 * p + 1];
        u16x8 o;
        o[0] = f2b(a.x); o[1] = f2b(a.y); o[2] = f2b(a.z); o[3] = f2b(a.w);
        o[4] = f2b(b.x); o[5] = f2b(b.y); o[6] = f2b(b.z); o[7] = f2b(b.w);
        *(u16x8*)&Bs[(p * 32 + srow) * 64 + wslot * 8] = o;
    }
}

// ---------------- x -> bf16 (only remaining conversion pass, 16 MB) ----------------
__global__ void cvt_f2b(const float4* __restrict__ src, unsigned short* __restrict__ dst, int n8) {
    int stride = gridDim.x * blockDim.x;
    for (int i = blockIdx.x * blockDim.x + threadIdx.x; i < n8; i += stride) {
        float4 a = src[2 * (size_t)i];
        float4 b = src[2 * (size_t)i + 1];
        u16x8 o;
        o[0] = f2b(a.x); o[1] = f2b(a.y); o[2] = f2b(a.z); o[3] = f2b(a.w);
        o[4] = f2b(b.x); o[5] = f2b(b.y); o[6] = f2b(b.z); o[7] = f2b(b.w);
        *(u16x8*)&dst[(size_t)i * 8] = o;
    }
}

// ---------------- gate scores: scores[T,E] = sigmoid(x @ gw^T), fp32 ----------------
#define SCT 8
#define SCK 128
__global__ __launch_bounds__(256) void gate_scores_kernel(
    const float* __restrict__ x, const float* __restrict__ gw, float* __restrict__ scores)
{
    __shared__ float xs[SCT * SCK];            // 8 x 128
    __shared__ float gs[NEXP * (SCK + 1)];     // 32 x 129 (pad: conflict-free)
    const int t0 = blockIdx.x * SCT;
    const int tid = threadIdx.x;
    const int tl = tid >> 5, e = tid & 31;
    float acc = 0.f;
    for (int k0 = 0; k0 < DIMSZ; k0 += SCK) {
        {
            int row = tid >> 5, d4 = tid & 31;
            *(float4*)&xs[row * SCK + d4 * 4] =
                *(const float4*)&x[(size_t)(t0 + row) * DIMSZ + k0 + d4 * 4];
        }
        #pragma unroll
        for (int i = 0; i < 4; ++i) {
            int lin = tid + i * 256;
            int row = lin >> 5, d4 = lin & 31;
            float4 v = *(const float4*)&gw[(size_t)row * DIMSZ + k0 + d4 * 4];
            float* dst = &gs[row * (SCK + 1) + d4 * 4];
            dst[0] = v.x; dst[1] = v.y; dst[2] = v.z; dst[3] = v.w;
        }
        __syncthreads();
        #pragma unroll 8
        for (int d = 0; d < SCK; ++d)
            acc += xs[tl * SCK + d] * gs[e * (SCK + 1) + d];
        __syncthreads();
    }
    scores[(size_t)(t0 + tl) * NEXP + e] = 1.f / (1.f + expf(-acc));
}

// ---------------- top-k routing (one thread per token) ----------------
__global__ __launch_bounds__(256) void topk_kernel(
    const float* __restrict__ scores,
    int* __restrict__ counts, int* __restrict__ toklist, float* __restrict__ wgts)
{
    int t = blockIdx.x * 256 + threadIdx.x;
    if (t >= T_TOK) return;
    float sc[NEXP];
    #pragma unroll
    for (int e = 0; e < NEXP; ++e) sc[e] = scores[(size_t)t * NEXP + e];

    float gsc[8];
    #pragma unroll
    for (int g = 0; g < 8; ++g) {
        float m = sc[4 * g];
        #pragma unroll
        for (int j = 1; j < 4; ++j) m = fmaxf(m, sc[4 * g + j]);
        gsc[g] = m;
    }
    bool gsel[8] = {false, false, false, false, false, false, false, false};
    for (int it = 0; it < 4; ++it) {
        int bi = -1; float bv = -1e30f;
        #pragma unroll
        for (int g = 0; g < 8; ++g)
            if (!gsel[g] && gsc[g] > bv) { bv = gsc[g]; bi = g; }
        gsel[bi] = true;
    }
    bool esel[NEXP];
    #pragma unroll
    for (int e = 0; e < NEXP; ++e) esel[e] = false;
    int   idx[NTOPK];
    float w[NTOPK];
    float sum = 0.f;
    for (int it = 0; it < NTOPK; ++it) {
        int bi = -1; float bv = -1e30f;
        #pragma unroll
        for (int e = 0; e < NEXP; ++e) {
            if (!gsel[e >> 2] || esel[e]) continue;
            if (sc[e] > bv) { bv = sc[e]; bi = e; }
        }
        esel[bi] = true; idx[it] = bi; w[it] = bv; sum += bv;
    }
    float scale = 2.5f / sum;
    for (int k = 0; k < NTOPK; ++k) {
        int e = idx[k];
        int s = atomicAdd(&counts[e], 1);
        toklist[e * T_TOK + s] = (t << 3) | k;
        wgts[e * T_TOK + s]   = w[k] * scale;
    }
}

// =======================================================================
// fc1_all: shared tiles first (wgid<256), routed expert-major after.
// B1/B2: raw f32, reg-prefetched one K-step ahead (loads fly during
// MFMA, land at the tail barrier). A: bf16 gl_lds, DOUBLE-BUFFERED LDS
// (next-step DMA issued alongside the B prefetch).
// H = silu(A@B1^T) * (A@B2^T), bf16 out.
// =======================================================================
__global__ __launch_bounds__(256, 2) void fc1_all(
    const unsigned short* __restrict__ A,
    const float* __restrict__ w11, const float* __restrict__ w33,
    const float* __restrict__ sw1, const float* __restrict__ sw3,
    unsigned short* __restrict__ h, unsigned short* __restrict__ hs,
    const int* __restrict__ counts, const int* __restrict__ toklist)
{
    constexpr int BM = 128, BN = 128, BK = 64, LDK = 64, K = DIMSZ;
    constexpr int ATILE = BM * LDK;
    __shared__ unsigned short As[2 * ATILE];
    __shared__ unsigned short B1s[BN * LDK];
    __shared__ unsigned short B2s[BN * LDK];
    __shared__ int aRowS[BM];
    __shared__ int cRowS[BM];
    __shared__ int map[4];   // {isShared, e, ytile, xtile}

    const int tid = threadIdx.x;
    if (tid == 0) {
        const int wgid = blockIdx.x;
        if (wgid < 256) {
            map[0] = 1; map[1] = NEXP; map[2] = wgid >> 4; map[3] = wgid & 15;
        } else {
            const int rid = wgid - 256;          // routed tile id
            const int xt = rid & 7, ty = rid >> 3;
            int acc2 = 0, fe = -1, fy = 0;
            #pragma unroll
            for (int e2 = 0; e2 < NEXP; ++e2) {
                const int nt = (counts[e2] + 127) >> 7;
                if (fe < 0 && ty < acc2 + nt) { fe = e2; fy = ty - acc2; }
                acc2 += nt;
            }
            map[0] = 0; map[1] = fe; map[2] = fy; map[3] = xt;
        }
    }
    __syncthreads();
    const bool SH = (map[0] != 0);
    const int e  = map[1];
    if (!SH && e < 0) return;            // beyond total routed tiles (uniform)
    const int m0 = map[2] * BM;
    const int n0 = map[3] * BN;
    const int N  = SH ? SINTER : INTERS;
    const int M  = SH ? T_TOK : counts[e];

    const size_t eoff = SH ? 0 : (size_t)e * INTERS * DIMSZ;
    const float* B1 = (SH ? sw1 : w11) + eoff;
    const float* B2 = (SH ? sw3 : w33) + eoff;
    unsigned short* Hout = SH ? hs : h;

    if (tid < BM) {
        int r = m0 + tid;
        if (SH) { aRowS[tid] = r; cRowS[tid] = r; }
        else if (r < M) {
            int ent = toklist[e * T_TOK + r];
            int t = ent >> 3, k = ent & 7;
            aRowS[tid] = t; cRowS[tid] = t * NTOPK + k;
        } else { aRowS[tid] = 0; cRowS[tid] = -1; }
    }
    __syncthreads();

    f32x4 acc1[4][4] = {};
    f32x4 acc2v[4][4] = {};

    const int wave = tid >> 6;
    const int lane = tid & 63;
    const int wm = (wave >> 1) * 64;
    const int wn = (wave & 1) * 64;
    const int lm = lane & 15;
    const int quad = lane >> 4;
    const int srow = tid >> 3;           // B staging row within pass
    const int sct  = tid & 7;            // B staging 16B slot
    const int wslot = sct ^ (srow & 7);  // swizzled write slot

    // A: per-lane pre-swizzled gl_lds pointers (4 chunks of 8 rows each)
    const unsigned short* aP[4];
    {
        const int l8 = lane >> 3;
        const int sg = (lane & 7) ^ l8;
        #pragma unroll
        for (int i = 0; i < 4; ++i) {
            const int c = wave * 4 + i;
            const int r = c * 8 + l8;
            aP[i] = A + (size_t)aRowS[r] * K + sg * 8;
        }
    }

    // prologue: prefetch step 0
    float4 r1[8], r2[8];
    load_b8(B1, n0, K, 0, srow, sct, r1);
    load_b8(B2, n0, K, 0, srow, sct, r2);
    #pragma unroll
    for (int i = 0; i < 4; ++i)
        gl_lds16(aP[i], &As[(wave * 4 + i) * 512]);

    int buf = 0;
    for (int k0 = 0; k0 < K; k0 += BK) {
        // write staged B (waits on its loads), A(k0) DMA drains at barrier
        write_b8(B1s, srow, wslot, r1);
        write_b8(B2s, srow, wslot, r2);
        __syncthreads();

        // prefetch step k0+BK: B loads + A DMA fly during the MFMA phase
        if (k0 + BK < K) {
            #pragma unroll
            for (int i = 0; i < 4; ++i)
                gl_lds16(aP[i] + k0 + BK, &As[(buf ^ 1) * ATILE + (wave * 4 + i) * 512]);
            load_b8(B1, n0, K, k0 + BK, srow, sct, r1);
            load_b8(B2, n0, K, k0 + BK, srow, sct, r2);
        }

        const unsigned short* Ac = &As[buf * ATILE];
        #pragma unroll
        for (int kh = 0; kh < 2; ++kh) {
            const int soff = (((kh << 2) | quad) ^ (lm & 7)) << 3;
            bf16x8 af[4], bf1[4], bf2[4];
            #pragma unroll
            for (int ti = 0; ti < 4; ++ti)
                af[ti] = *(const bf16x8*)&Ac[(wm + ti * 16 + lm) * LDK + soff];
            #pragma unroll
            for (int tj = 0; tj < 4; ++tj) {
                bf1[tj] = *(const bf16x8*)&B1s[(wn + tj * 16 + lm) * LDK + soff];
                bf2[tj] = *(const bf16x8*)&B2s[(wn + tj * 16 + lm) * LDK + soff];
            }
            #pragma unroll
            for (int ti = 0; ti < 4; ++ti)
                #pragma unroll
                for (int tj = 0; tj < 4; ++tj) {
                    acc1[ti][tj] = __builtin_amdgcn_mfma_f32_16x16x32_bf16(
                        af[ti], bf1[tj], acc1[ti][tj], 0, 0, 0);
                    acc2v[ti][tj] = __builtin_amdgcn_mfma_f32_16x16x32_bf16(
                        af[ti], bf2[tj], acc2v[ti][tj], 0, 0, 0);
                }
        }
        __syncthreads();   // MFMA done; prefetched loads/DMA drained here
        buf ^= 1;
    }

    #pragma unroll
    for (int ti = 0; ti < 4; ++ti) {
        #pragma unroll
        for (int r = 0; r < 4; ++r) {
            int lrow = wm + ti * 16 + quad * 4 + r;
            int cr = cRowS[lrow];
            if (cr < 0) continue;
            #pragma unroll
            for (int tj = 0; tj < 4; ++tj) {
                int nn = n0 + wn + tj * 16 + lm;
                float g = acc1[ti][tj][r];
                float u = acc2v[ti][tj][r];
                float hv = g / (1.f + expf(-g)) * u;
                Hout[(size_t)cr * N + nn] = f2b(hv);
            }
        }
    }
}

// =======================================================================
// fc2_all: B = raw f32 (w22/sw2), same prefetch pipeline (1 tensor);
// A = h/hs bf16 gl_lds, double-buffered.
// MODE 0: merged dense (shared->out store, routed->yexp slot store).
// MODE 1: shared only (grid 256).  MODE 2: routed only, atomic into out.
// =======================================================================
template <int MODE>
__global__ __launch_bounds__(256, 3) void fc2_all(
    const unsigned short* __restrict__ h, const unsigned short* __restrict__ hs,
    const float* __restrict__ w22, const float* __restrict__ sw2,
    float* __restrict__ yexp, float* __restrict__ out,
    const int* __restrict__ counts, const int* __restrict__ toklist,
    const float* __restrict__ wgts)
{
    constexpr int BM = 128, BN = 128, BK = 64, LDK = 64;
    constexpr int ATILE = BM * LDK;
    __shared__ unsigned short As[2 * ATILE];
    __shared__ unsigned short Bs[BN * LDK];
    __shared__ int   aRowS[BM];
    __shared__ int   cRowS[BM];
    __shared__ float cWS[BM];
    __shared__ int   map[4];

    const int tid = threadIdx.x;
    if (tid == 0) {
        const int wgid = blockIdx.x;
        if (MODE == 1 || (MODE == 0 && wgid < 256)) {
            const int sid = wgid;
            map[0] = 1; map[1] = NEXP; map[2] = sid >> 4; map[3] = sid & 15;
        } else {
            const int rid = (MODE == 0) ? (wgid - 256) : wgid;
            const int xt = rid & 15, ty = rid >> 4;
            int acc2 = 0, fe = -1, fy = 0;
            #pragma unroll
            for (int e2 = 0; e2 < NEXP; ++e2) {
                const int nt = (counts[e2] + 127) >> 7;
                if (fe < 0 && ty < acc2 + nt) { fe = e2; fy = ty - acc2; }
                acc2 += nt;
            }
            map[0] = 0; map[1] = fe; map[2] = fy; map[3] = xt;
        }
    }
    __syncthreads();
    const bool SH = (map[0] != 0);
    const int e  = map[1];
    if (!SH && e < 0) return;
    const int m0 = map[2] * BM;
    const int n0 = map[3] * BN;
    const int K  = SH ? SINTER : INTERS;
    const int M  = SH ? T_TOK : counts[e];

    const unsigned short* Asrc = SH ? hs : h;   // row stride == K for both
    const float* B = SH ? sw2 : (w22 + (size_t)e * DIMSZ * INTERS);
    float* C = SH ? out : ((MODE == 2) ? out : yexp);

    if (tid < BM) {
        int r = m0 + tid;
        if (SH) { aRowS[tid] = r; cRowS[tid] = r; cWS[tid] = 1.f; }
        else if (r < M) {
            int ent = toklist[e * T_TOK + r];
            int slot = (ent >> 3) * NTOPK + (ent & 7);
            aRowS[tid] = slot;
            cRowS[tid] = (MODE == 2) ? (ent >> 3) : slot;
            cWS[tid] = wgts[e * T_TOK + r];
        } else { aRowS[tid] = 0; cRowS[tid] = -1; cWS[tid] = 0.f; }
    }
    __syncthreads();

    f32x4 acc[4][4] = {};

    const int wave = tid >> 6;
    const int lane = tid & 63;
    const int wm = (wave >> 1) * 64;
    const int wn = (wave & 1) * 64;
    const int lm = lane & 15;
    const int quad = lane >> 4;
    const int srow = tid >> 3;
    const int sct  = tid & 7;
    const int wslot = sct ^ (srow & 7);

    const unsigned short* aP[4];
    {
        const int l8 = lane >> 3;
        const int sg = (lane & 7) ^ l8;
        #pragma unroll
        for (int i = 0; i < 4; ++i) {
            const int c = wave * 4 + i;
            const int r = c * 8 + l8;
            aP[i] = Asrc + (size_t)aRowS[r] * K + sg * 8;
        }
    }

    float4 rb[8];
    load_b8(B, n0, K, 0, srow, sct, rb);
    #pragma unroll
    for (int i = 0; i < 4; ++i)
        gl_lds16(aP[i], &As[(wave * 4 + i) * 512]);

    int buf = 0;
    for (int k0 = 0; k0 < K; k0 += BK) {
        write_b8(Bs, srow, wslot, rb);
        __syncthreads();

        if (k0 + BK < K) {
            #pragma unroll
            for (int i = 0; i < 4; ++i)
                gl_lds16(aP[i] + k0 + BK, &As[(buf ^ 1) * ATILE + (wave * 4 + i) * 512]);
            load_b8(B, n0, K, k0 + BK, srow, sct, rb);
        }

        const unsigned short* Ac = &As[buf * ATILE];
        #pragma unroll
        for (int kh = 0; kh < 2; ++kh) {
            const int soff = (((kh << 2) | quad) ^ (lm & 7)) << 3;
            bf16x8 af[4], bfr[4];
            #pragma unroll
            for (int ti = 0; ti < 4; ++ti)
                af[ti] = *(const bf16x8*)&Ac[(wm + ti * 16 + lm) * LDK + soff];
            #pragma unroll
            for (int tj = 0; tj < 4; ++tj)
                bfr[tj] = *(const bf16x8*)&Bs[(wn + tj * 16 + lm) * LDK + soff];
            #pragma unroll
            for (int ti = 0; ti < 4; ++ti)
                #pragma unroll
                for (int tj = 0; tj < 4; ++tj)
                    acc[ti][tj] = __builtin_amdgcn_mfma_f32_16x16x32_bf16(
                        af[ti], bfr[tj], acc[ti][tj], 0, 0, 0);
        }
        __syncthreads();
        buf ^= 1;
    }

    #pragma unroll
    for (int ti = 0; ti < 4; ++ti) {
        #pragma unroll
        for (int r = 0; r < 4; ++r) {
            int lrow = wm + ti * 16 + quad * 4 + r;
            int cr = cRowS[lrow];
            if (cr < 0) continue;
            #pragma unroll
            for (int tj = 0; tj < 4; ++tj) {
                int nn = n0 + wn + tj * 16 + lm;
                float v = acc[ti][tj][r] * cWS[lrow];
                if (MODE == 2 && !SH)
                    atomicAdd(&C[(size_t)cr * DIMSZ + nn], v);
                else
                    C[(size_t)cr * DIMSZ + nn] = v;
            }
        }
    }
}

// ---------------- combine: out[t,:] += sum_k yexp[t*6+k,:] ----------------
__global__ __launch_bounds__(256) void combine_kernel(
    const float4* __restrict__ yexp, float4* __restrict__ out, int n4)
{
    const int D4 = DIMSZ / 4;   // 512
    int stride = gridDim.x * blockDim.x;
    for (int i = blockIdx.x * blockDim.x + threadIdx.x; i < n4; i += stride) {
        int t = i / D4, d4 = i - t * D4;
        const float4* r = yexp + (size_t)t * NTOPK * D4 + d4;
        float4 a = out[i];
        #pragma unroll
        for (int k = 0; k < NTOPK; ++k) {
            float4 s = r[(size_t)k * D4];
            a.x += s.x; a.y += s.y; a.z += s.z; a.w += s.w;
        }
        out[i] = a;
    }
}

extern "C" void kernel_launch(void* const* d_in, const int* in_sizes, int n_in,
                              void* d_out, int out_size, void* d_ws, size_t ws_size,
                              hipStream_t stream)
{
    const float* x   = (const float*)d_in[0];
    const float* gw  = (const float*)d_in[1];
    const float* w11 = (const float*)d_in[2];
    const float* w33 = (const float*)d_in[3];
    const float* w22 = (const float*)d_in[4];
    const float* sw1 = (const float*)d_in[5];
    const float* sw2 = (const float*)d_in[6];
    const float* sw3 = (const float*)d_in[7];
    float* out = (float*)d_out;

    char* ws = (char*)d_ws;
    size_t off = 0;
    auto alloc = [&](size_t b) { void* p = ws + off; off = (off + b + 255) & ~(size_t)255; return p; };
    int*            counts  = (int*)alloc(NEXP * 4);
    int*            toklist = (int*)alloc((size_t)NEXP * T_TOK * 4);
    float*          wgts    = (float*)alloc((size_t)NEXP * T_TOK * 4);
    float*          scores  = (float*)alloc((size_t)T_TOK * NEXP * 4);
    unsigned short* xb      = (unsigned short*)alloc((size_t)T_TOK * DIMSZ * 2);
    unsigned short* h       = (unsigned short*)alloc((size_t)T_TOK * NTOPK * INTERS * 2);
    unsigned short* hs      = (unsigned short*)alloc((size_t)T_TOK * SINTER * 2);

    const size_t yBytes = (size_t)T_TOK * NTOPK * DIMSZ * 4;   // 100.7 MB
    const bool DENSE = (off + yBytes + 256) <= ws_size;
    float* yexp = DENSE ? (float*)alloc(yBytes) : nullptr;

    hipMemsetAsync(counts, 0, NEXP * 4, stream);

    const int n4x = T_TOK * DIMSZ / 4;
    cvt_f2b<<<1024, 256, 0, stream>>>((const float4*)x, xb, T_TOK * DIMSZ / 8);

    gate_scores_kernel<<<T_TOK / SCT, 256, 0, stream>>>(x, gw, scores);
    topk_kernel<<<(T_TOK + 255) / 256, 256, 0, stream>>>(scores, counts, toklist, wgts);

    // shared tiles first (256 = 1/CU), routed tiles fill remaining slots
    fc1_all<<<256 + 1024, 256, 0, stream>>>(
        xb, w11, w33, sw1, sw3, h, hs, counts, toklist);

    if (DENSE) {
        fc2_all<0><<<256 + 2048, 256, 0, stream>>>(
            h, hs, w22, sw2, yexp, out, counts, toklist, wgts);
        combine_kernel<<<2048, 256, 0, stream>>>((const float4*)yexp, (float4*)out, n4x);
    } else {
        // fallback: shared overwrites out first, then routed atomically adds
        fc2_all<1><<<256, 256, 0, stream>>>(
            h, hs, w22, sw2, nullptr, out, counts, toklist, wgts);
        fc2_all<2><<<2048, 256, 0, stream>>>(
            h, hs, w22, sw2, nullptr, out, counts, toklist, wgts);
    }
}

// Round 9
// 1102.267 us; speedup vs baseline: 1.1485x; 1.1485x over previous
//
#include <hip/hip_runtime.h>
#include <hip/hip_bf16.h>

#define T_TOK  2048
#define DIMSZ  2048
#define NEXP   32
#define INTERS 1024
#define SINTER 2048
#define NTOPK  6

typedef __bf16 bf16x8 __attribute__((ext_vector_type(8)));
typedef float  f32x4  __attribute__((ext_vector_type(4)));
typedef unsigned short u16x8 __attribute__((ext_vector_type(8)));

__device__ __forceinline__ unsigned short f2b(float f) {
    __hip_bfloat16 h = __float2bfloat16(f);
    return __builtin_bit_cast(unsigned short, h);
}

// async global->LDS, 16B per lane. LDS dest is wave-uniform base + lane*16.
__device__ __forceinline__ void gl_lds16(const unsigned short* g, unsigned short* l) {
    __builtin_amdgcn_global_load_lds(
        (const __attribute__((address_space(1))) void*)g,
        (__attribute__((address_space(3))) void*)l, 16, 0, 0);
}
__device__ __forceinline__ void gl_lds16f(const float* g, float* l) {
    __builtin_amdgcn_global_load_lds(
        (const __attribute__((address_space(1))) void*)g,
        (__attribute__((address_space(3))) void*)l, 16, 0, 0);
}

// 8 f32 -> bf16x8 fragment
__device__ __forceinline__ bf16x8 cvt8(float4 lo, float4 hi) {
    u16x8 u;
    u[0] = f2b(lo.x); u[1] = f2b(lo.y); u[2] = f2b(lo.z); u[3] = f2b(lo.w);
    u[4] = f2b(hi.x); u[5] = f2b(hi.y); u[6] = f2b(hi.z); u[7] = f2b(hi.w);
    return __builtin_bit_cast(bf16x8, u);
}

// ---------------- x -> bf16 (only conversion pass, 16 MB) ----------------
__global__ void cvt_f2b(const float4* __restrict__ src, unsigned short* __restrict__ dst, int n8) {
    int stride = gridDim.x * blockDim.x;
    for (int i = blockIdx.x * blockDim.x + threadIdx.x; i < n8; i += stride) {
        float4 a = src[2 * (size_t)i];
        float4 b = src[2 * (size_t)i + 1];
        u16x8 o;
        o[0] = f2b(a.x); o[1] = f2b(a.y); o[2] = f2b(a.z); o[3] = f2b(a.w);
        o[4] = f2b(b.x); o[5] = f2b(b.y); o[6] = f2b(b.z); o[7] = f2b(b.w);
        *(u16x8*)&dst[(size_t)i * 8] = o;
    }
}

// ---------------- gate scores: scores[T,E] = sigmoid(x @ gw^T), fp32 ----------------
#define SCT 8
#define SCK 128
__global__ __launch_bounds__(256) void gate_scores_kernel(
    const float* __restrict__ x, const float* __restrict__ gw, float* __restrict__ scores)
{
    __shared__ float xs[SCT * SCK];            // 8 x 128
    __shared__ float gs[NEXP * (SCK + 1)];     // 32 x 129 (pad: conflict-free)
    const int t0 = blockIdx.x * SCT;
    const int tid = threadIdx.x;
    const int tl = tid >> 5, e = tid & 31;
    float acc = 0.f;
    for (int k0 = 0; k0 < DIMSZ; k0 += SCK) {
        {
            int row = tid >> 5, d4 = tid & 31;
            *(float4*)&xs[row * SCK + d4 * 4] =
                *(const float4*)&x[(size_t)(t0 + row) * DIMSZ + k0 + d4 * 4];
        }
        #pragma unroll
        for (int i = 0; i < 4; ++i) {
            int lin = tid + i * 256;
            int row = lin >> 5, d4 = lin & 31;
            float4 v = *(const float4*)&gw[(size_t)row * DIMSZ + k0 + d4 * 4];
            float* dst = &gs[row * (SCK + 1) + d4 * 4];
            dst[0] = v.x; dst[1] = v.y; dst[2] = v.z; dst[3] = v.w;
        }
        __syncthreads();
        #pragma unroll 8
        for (int d = 0; d < SCK; ++d)
            acc += xs[tl * SCK + d] * gs[e * (SCK + 1) + d];
        __syncthreads();
    }
    scores[(size_t)(t0 + tl) * NEXP + e] = 1.f / (1.f + expf(-acc));
}

// ---------------- top-k routing (one thread per token) ----------------
__global__ __launch_bounds__(256) void topk_kernel(
    const float* __restrict__ scores,
    int* __restrict__ counts, int* __restrict__ toklist, float* __restrict__ wgts)
{
    int t = blockIdx.x * 256 + threadIdx.x;
    if (t >= T_TOK) return;
    float sc[NEXP];
    #pragma unroll
    for (int e = 0; e < NEXP; ++e) sc[e] = scores[(size_t)t * NEXP + e];

    float gsc[8];
    #pragma unroll
    for (int g = 0; g < 8; ++g) {
        float m = sc[4 * g];
        #pragma unroll
        for (int j = 1; j < 4; ++j) m = fmaxf(m, sc[4 * g + j]);
        gsc[g] = m;
    }
    bool gsel[8] = {false, false, false, false, false, false, false, false};
    for (int it = 0; it < 4; ++it) {
        int bi = -1; float bv = -1e30f;
        #pragma unroll
        for (int g = 0; g < 8; ++g)
            if (!gsel[g] && gsc[g] > bv) { bv = gsc[g]; bi = g; }
        gsel[bi] = true;
    }
    bool esel[NEXP];
    #pragma unroll
    for (int e = 0; e < NEXP; ++e) esel[e] = false;
    int   idx[NTOPK];
    float w[NTOPK];
    float sum = 0.f;
    for (int it = 0; it < NTOPK; ++it) {
        int bi = -1; float bv = -1e30f;
        #pragma unroll
        for (int e = 0; e < NEXP; ++e) {
            if (!gsel[e >> 2] || esel[e]) continue;
            if (sc[e] > bv) { bv = sc[e]; bi = e; }
        }
        esel[bi] = true; idx[it] = bi; w[it] = bv; sum += bv;
    }
    float scale = 2.5f / sum;
    for (int k = 0; k < NTOPK; ++k) {
        int e = idx[k];
        int s = atomicAdd(&counts[e], 1);
        toklist[e * T_TOK + s] = (t << 3) | k;
        wgts[e * T_TOK + s]   = w[k] * scale;
    }
}

// per-thread (uniform) tile decode: shared tiles first, routed expert-major
__device__ __forceinline__ void decode_tile(
    int wgid, int xt_bits, const int* __restrict__ counts,
    bool& SH, int& e, int& m0, int& n0)
{
    if (wgid < 256) {
        SH = true; e = NEXP; m0 = (wgid >> 4) * 128; n0 = (wgid & 15) * 128;
        return;
    }
    const int rid = wgid - 256;
    const int xmask = (1 << xt_bits) - 1;
    const int xt = rid & xmask, ty = rid >> xt_bits;
    int acc2 = 0, fe = -1, fy = 0;
    #pragma unroll
    for (int e2 = 0; e2 < NEXP; ++e2) {
        const int nt = (counts[e2] + 127) >> 7;
        if (fe < 0 && ty < acc2 + nt) { fe = e2; fy = ty - acc2; }
        acc2 += nt;
    }
    SH = false; e = fe; m0 = fy * 128; n0 = xt * 128;
}

// =======================================================================
// fc1_all: shared tiles first (wgid<256), routed expert-major after.
// B1/B2 staged as RAW F32 via global_load_lds (pure DMA, no reg staging,
// no spill); converted to bf16 on the LDS->fragment read. A bf16 gl_lds.
// Swizzle: global granule (l&15)^(row&7) -> linear LDS; read granule
// j ^ (lm&7). LDS exactly 80 KB -> 2 blocks/CU (no LDS helper arrays).
// H = silu(A@B1^T) * (A@B2^T), bf16 out.
// =======================================================================
__global__ __launch_bounds__(256, 2) void fc1_all(
    const unsigned short* __restrict__ A,
    const float* __restrict__ w11, const float* __restrict__ w33,
    const float* __restrict__ sw1, const float* __restrict__ sw3,
    unsigned short* __restrict__ h, unsigned short* __restrict__ hs,
    const int* __restrict__ counts, const int* __restrict__ toklist)
{
    constexpr int BM = 128, BN = 128, BK = 64, LDK = 64, K = DIMSZ;
    __shared__ unsigned short As[BM * LDK];   // bf16, 16 KB
    __shared__ float B1s[BN * BK];            // f32, 32 KB
    __shared__ float B2s[BN * BK];            // f32, 32 KB

    const int tid = threadIdx.x;
    bool SH; int e, m0, n0;
    decode_tile(blockIdx.x, 3, counts, SH, e, m0, n0);   // routed: 8 x-tiles
    if (!SH && e < 0) return;
    const int N = SH ? SINTER : INTERS;
    const int M = SH ? T_TOK : counts[e];

    const size_t eoff = SH ? 0 : (size_t)e * INTERS * DIMSZ;
    const float* B1 = (SH ? sw1 : w11) + eoff + (size_t)n0 * K;
    const float* B2 = (SH ? sw3 : w33) + eoff + (size_t)n0 * K;
    unsigned short* Hout = SH ? hs : h;

    const int wave = tid >> 6;
    const int lane = tid & 63;
    const int wm = (wave >> 1) * 64;
    const int wn = (wave & 1) * 64;
    const int lm = lane & 15;
    const int quad = lane >> 4;

    // A: per-lane pre-swizzled gl_lds pointers (4 chunks of 8 rows each)
    const unsigned short* aP[4];
    {
        const int l8 = lane >> 3;
        const int sg = (lane & 7) ^ l8;
        #pragma unroll
        for (int i = 0; i < 4; ++i) {
            const int r = (wave * 4 + i) * 8 + l8;
            int gr = m0 + r;
            int ar;
            if (SH) ar = gr;
            else ar = (gr < M) ? (toklist[e * T_TOK + gr] >> 3) : 0;
            aP[i] = A + (size_t)ar * K + sg * 8;
        }
    }
    // B: per-lane pre-swizzled f32 source offsets (8 chunks of 4 rows each)
    int offB[8];
    {
        #pragma unroll
        for (int i = 0; i < 8; ++i) {
            const int c = wave * 8 + i;
            const int row = 4 * c + (lane >> 4);
            const int g = (lane & 15) ^ (row & 7);
            offB[i] = row * K + g * 4;
        }
    }

    f32x4 acc1[4][4] = {};
    f32x4 acc2v[4][4] = {};

    for (int k0 = 0; k0 < K; k0 += BK) {
        #pragma unroll
        for (int i = 0; i < 4; ++i)
            gl_lds16(aP[i] + k0, &As[(wave * 4 + i) * 512]);
        #pragma unroll
        for (int i = 0; i < 8; ++i) {
            const int c = wave * 8 + i;
            gl_lds16f(B1 + offB[i] + k0, &B1s[c * 256]);
            gl_lds16f(B2 + offB[i] + k0, &B2s[c * 256]);
        }
        __syncthreads();   // drains vmcnt(0): all DMA visible
        #pragma unroll
        for (int kh = 0; kh < 2; ++kh) {
            const int soffA = (((kh << 2) | quad) ^ (lm & 7)) << 3;
            const int j0 = ((kh << 2) | quad) << 1;
            const int s0 = j0 ^ (lm & 7);
            const int s1 = (j0 | 1) ^ (lm & 7);
            bf16x8 af[4], bf1[4], bf2[4];
            #pragma unroll
            for (int ti = 0; ti < 4; ++ti)
                af[ti] = *(const bf16x8*)&As[(wm + ti * 16 + lm) * LDK + soffA];
            #pragma unroll
            for (int tj = 0; tj < 4; ++tj) {
                const int rB = (wn + tj * 16 + lm) * 64;
                float4 lo1 = *(const float4*)&B1s[rB + s0 * 4];
                float4 hi1 = *(const float4*)&B1s[rB + s1 * 4];
                bf1[tj] = cvt8(lo1, hi1);
                float4 lo2 = *(const float4*)&B2s[rB + s0 * 4];
                float4 hi2 = *(const float4*)&B2s[rB + s1 * 4];
                bf2[tj] = cvt8(lo2, hi2);
            }
            #pragma unroll
            for (int ti = 0; ti < 4; ++ti)
                #pragma unroll
                for (int tj = 0; tj < 4; ++tj) {
                    acc1[ti][tj] = __builtin_amdgcn_mfma_f32_16x16x32_bf16(
                        af[ti], bf1[tj], acc1[ti][tj], 0, 0, 0);
                    acc2v[ti][tj] = __builtin_amdgcn_mfma_f32_16x16x32_bf16(
                        af[ti], bf2[tj], acc2v[ti][tj], 0, 0, 0);
                }
        }
        __syncthreads();
    }

    #pragma unroll
    for (int ti = 0; ti < 4; ++ti) {
        #pragma unroll
        for (int r = 0; r < 4; ++r) {
            const int lrow = wm + ti * 16 + quad * 4 + r;
            const int grow = m0 + lrow;
            int cr;
            if (SH) cr = grow;
            else {
                if (grow >= M) continue;
                int ent = toklist[e * T_TOK + grow];
                cr = (ent >> 3) * NTOPK + (ent & 7);
            }
            #pragma unroll
            for (int tj = 0; tj < 4; ++tj) {
                int nn = n0 + wn + tj * 16 + lm;
                float g = acc1[ti][tj][r];
                float u = acc2v[ti][tj][r];
                float hv = g / (1.f + expf(-g)) * u;
                Hout[(size_t)cr * N + nn] = f2b(hv);
            }
        }
    }
}

// =======================================================================
// fc2_all: B = raw f32 (w22/sw2) via gl_lds + read-side cvt; A = h/hs
// bf16 gl_lds. LDS 48 KB -> 3 blocks/CU.
// MODE 0: merged dense (shared->out store, routed->yexp slot store).
// MODE 1: shared only (grid 256).  MODE 2: routed only, atomic into out.
// =======================================================================
template <int MODE>
__global__ __launch_bounds__(256, 3) void fc2_all(
    const unsigned short* __restrict__ h, const unsigned short* __restrict__ hs,
    const float* __restrict__ w22, const float* __restrict__ sw2,
    float* __restrict__ yexp, float* __restrict__ out,
    const int* __restrict__ counts, const int* __restrict__ toklist,
    const float* __restrict__ wgts)
{
    constexpr int BM = 128, BN = 128, BK = 64, LDK = 64;
    __shared__ unsigned short As[BM * LDK];   // 16 KB
    __shared__ float Bs[BN * BK];             // 32 KB

    const int tid = threadIdx.x;
    bool SH; int e, m0, n0;
    {
        int wgid = blockIdx.x;
        if (MODE == 1) { SH = true; e = NEXP; m0 = (wgid >> 4) * 128; n0 = (wgid & 15) * 128; }
        else if (MODE == 2) { decode_tile(wgid + 256, 4, counts, SH, e, m0, n0); }
        else decode_tile(wgid, 4, counts, SH, e, m0, n0);   // routed: 16 x-tiles
    }
    if (!SH && e < 0) return;
    const int K = SH ? SINTER : INTERS;
    const int M = SH ? T_TOK : counts[e];
    if (m0 >= M) return;

    const unsigned short* Asrc = SH ? hs : h;   // row stride == K
    const float* B = (SH ? sw2 : (w22 + (size_t)e * DIMSZ * INTERS)) + (size_t)n0 * K;
    float* C = SH ? out : ((MODE == 2) ? out : yexp);

    const int wave = tid >> 6;
    const int lane = tid & 63;
    const int wm = (wave >> 1) * 64;
    const int wn = (wave & 1) * 64;
    const int lm = lane & 15;
    const int quad = lane >> 4;

    const unsigned short* aP[4];
    {
        const int l8 = lane >> 3;
        const int sg = (lane & 7) ^ l8;
        #pragma unroll
        for (int i = 0; i < 4; ++i) {
            const int r = (wave * 4 + i) * 8 + l8;
            int gr = m0 + r;
            int ar;
            if (SH) ar = gr;
            else if (gr < M) {
                int ent = toklist[e * T_TOK + gr];
                ar = (ent >> 3) * NTOPK + (ent & 7);
            } else ar = 0;
            aP[i] = Asrc + (size_t)ar * K + sg * 8;
        }
    }
    int offB[8];
    {
        #pragma unroll
        for (int i = 0; i < 8; ++i) {
            const int c = wave * 8 + i;
            const int row = 4 * c + (lane >> 4);
            const int g = (lane & 15) ^ (row & 7);
            offB[i] = row * K + g * 4;
        }
    }

    f32x4 acc[4][4] = {};

    for (int k0 = 0; k0 < K; k0 += BK) {
        #pragma unroll
        for (int i = 0; i < 4; ++i)
            gl_lds16(aP[i] + k0, &As[(wave * 4 + i) * 512]);
        #pragma unroll
        for (int i = 0; i < 8; ++i) {
            const int c = wave * 8 + i;
            gl_lds16f(B + offB[i] + k0, &Bs[c * 256]);
        }
        __syncthreads();
        #pragma unroll
        for (int kh = 0; kh < 2; ++kh) {
            const int soffA = (((kh << 2) | quad) ^ (lm & 7)) << 3;
            const int j0 = ((kh << 2) | quad) << 1;
            const int s0 = j0 ^ (lm & 7);
            const int s1 = (j0 | 1) ^ (lm & 7);
            bf16x8 af[4], bfr[4];
            #pragma unroll
            for (int ti = 0; ti < 4; ++ti)
                af[ti] = *(const bf16x8*)&As[(wm + ti * 16 + lm) * LDK + soffA];
            #pragma unroll
            for (int tj = 0; tj < 4; ++tj) {
                const int rB = (wn + tj * 16 + lm) * 64;
                float4 lo = *(const float4*)&Bs[rB + s0 * 4];
                float4 hi = *(const float4*)&Bs[rB + s1 * 4];
                bfr[tj] = cvt8(lo, hi);
            }
            #pragma unroll
            for (int ti = 0; ti < 4; ++ti)
                #pragma unroll
                for (int tj = 0; tj < 4; ++tj)
                    acc[ti][tj] = __builtin_amdgcn_mfma_f32_16x16x32_bf16(
                        af[ti], bfr[tj], acc[ti][tj], 0, 0, 0);
        }
        __syncthreads();
    }

    #pragma unroll
    for (int ti = 0; ti < 4; ++ti) {
        #pragma unroll
        for (int r = 0; r < 4; ++r) {
            const int lrow = wm + ti * 16 + quad * 4 + r;
            const int grow = m0 + lrow;
            int cr; float cw;
            if (SH) { cr = grow; cw = 1.f; }
            else {
                if (grow >= M) continue;
                int ent = toklist[e * T_TOK + grow];
                cr = (MODE == 2) ? (ent >> 3) : ((ent >> 3) * NTOPK + (ent & 7));
                cw = wgts[e * T_TOK + grow];
            }
            #pragma unroll
            for (int tj = 0; tj < 4; ++tj) {
                int nn = n0 + wn + tj * 16 + lm;
                float v = acc[ti][tj][r] * cw;
                if (MODE == 2 && !SH)
                    atomicAdd(&C[(size_t)cr * DIMSZ + nn], v);
                else
                    C[(size_t)cr * DIMSZ + nn] = v;
            }
        }
    }
}

// ---------------- combine: out[t,:] += sum_k yexp[t*6+k,:] ----------------
__global__ __launch_bounds__(256) void combine_kernel(
    const float4* __restrict__ yexp, float4* __restrict__ out, int n4)
{
    const int D4 = DIMSZ / 4;   // 512
    int stride = gridDim.x * blockDim.x;
    for (int i = blockIdx.x * blockDim.x + threadIdx.x; i < n4; i += stride) {
        int t = i / D4, d4 = i - t * D4;
        const float4* r = yexp + (size_t)t * NTOPK * D4 + d4;
        float4 a = out[i];
        #pragma unroll
        for (int k = 0; k < NTOPK; ++k) {
            float4 s = r[(size_t)k * D4];
            a.x += s.x; a.y += s.y; a.z += s.z; a.w += s.w;
        }
        out[i] = a;
    }
}

extern "C" void kernel_launch(void* const* d_in, const int* in_sizes, int n_in,
                              void* d_out, int out_size, void* d_ws, size_t ws_size,
                              hipStream_t stream)
{
    const float* x   = (const float*)d_in[0];
    const float* gw  = (const float*)d_in[1];
    const float* w11 = (const float*)d_in[2];
    const float* w33 = (const float*)d_in[3];
    const float* w22 = (const float*)d_in[4];
    const float* sw1 = (const float*)d_in[5];
    const float* sw2 = (const float*)d_in[6];
    const float* sw3 = (const float*)d_in[7];
    float* out = (float*)d_out;

    char* ws = (char*)d_ws;
    size_t off = 0;
    auto alloc = [&](size_t b) { void* p = ws + off; off = (off + b + 255) & ~(size_t)255; return p; };
    int*            counts  = (int*)alloc(NEXP * 4);
    int*            toklist = (int*)alloc((size_t)NEXP * T_TOK * 4);
    float*          wgts    = (float*)alloc((size_t)NEXP * T_TOK * 4);
    float*          scores  = (float*)alloc((size_t)T_TOK * NEXP * 4);
    unsigned short* xb      = (unsigned short*)alloc((size_t)T_TOK * DIMSZ * 2);
    unsigned short* h       = (unsigned short*)alloc((size_t)T_TOK * NTOPK * INTERS * 2);
    unsigned short* hs      = (unsigned short*)alloc((size_t)T_TOK * SINTER * 2);

    const size_t yBytes = (size_t)T_TOK * NTOPK * DIMSZ * 4;   // 100.7 MB
    const bool DENSE = (off + yBytes + 256) <= ws_size;
    float* yexp = DENSE ? (float*)alloc(yBytes) : nullptr;

    hipMemsetAsync(counts, 0, NEXP * 4, stream);

    const int n4x = T_TOK * DIMSZ / 4;
    cvt_f2b<<<1024, 256, 0, stream>>>((const float4*)x, xb, T_TOK * DIMSZ / 8);

    gate_scores_kernel<<<T_TOK / SCT, 256, 0, stream>>>(x, gw, scores);
    topk_kernel<<<(T_TOK + 255) / 256, 256, 0, stream>>>(scores, counts, toklist, wgts);

    // shared tiles first (256 = 1/CU), routed tiles fill remaining slots
    fc1_all<<<256 + 1024, 256, 0, stream>>>(
        xb, w11, w33, sw1, sw3, h, hs, counts, toklist);

    if (DENSE) {
        fc2_all<0><<<256 + 2048, 256, 0, stream>>>(
            h, hs, w22, sw2, yexp, out, counts, toklist, wgts);
        combine_kernel<<<2048, 256, 0, stream>>>((const float4*)yexp, (float4*)out, n4x);
    } else {
        // fallback: shared overwrites out first, then routed atomically adds
        fc2_all<1><<<256, 256, 0, stream>>>(
            h, hs, w22, sw2, nullptr, out, counts, toklist, wgts);
        fc2_all<2><<<2048, 256, 0, stream>>>(
            h, hs, w22, sw2, nullptr, out, counts, toklist, wgts);
    }
}